// Round 5
// baseline (173.668 us; speedup 1.0000x reference)
//
#include <hip/hip_runtime.h>
#include <math.h>

#define B_ 16
#define C_ 256
#define L_ 2048

using short8 = __attribute__((ext_vector_type(8))) short;
using f32x4  = __attribute__((ext_vector_type(4))) float;
using f32x16 = __attribute__((ext_vector_type(16))) float;
typedef unsigned int uint;

__device__ __forceinline__ unsigned short f2bf(float f) {
  unsigned u = __float_as_uint(f);
  return (unsigned short)((u + 0x7FFFu + ((u >> 16) & 1u)) >> 16);
}

__device__ __forceinline__ void gload16(const void* src, void* dst) {
  __builtin_amdgcn_global_load_lds(
      (const __attribute__((address_space(1))) unsigned int*)src,
      (__attribute__((address_space(3))) unsigned int*)dst, 16, 0, 0);
}

// ---------------- kernel 0: convert weights fp32 -> bf16 ----------------
__global__ __launch_bounds__(256) void convert_w(const float* __restrict__ wt,
                                                 const float* __restrict__ wp,
                                                 const float* __restrict__ wg,
                                                 unsigned short* __restrict__ dst) {
  int i = blockIdx.x * 256 + threadIdx.x;          // 65536 per matrix
  dst[i]          = f2bf(wt[i]);
  dst[65536 + i]  = f2bf(wp[i]);
  dst[131072 + i] = f2bf(wg[i]);
}

// ---------------- kernel 1: fused QKV projection ----------------
// p=0: qT[b,l,o] = (W_theta x + b_theta) * log2e/16   (bf16, [B,L,C])
// p=1: kT[b,l,o] =  W_phi   x + b_phi                 (bf16, [B,L,C])
// p=2: v [b,o,l] =  W_g     x + b_g                   (bf16, [B,C,L])
__global__ __launch_bounds__(256, 2) void proj_kernel(
    const float* __restrict__ x, const unsigned short* __restrict__ wbf,
    const float* __restrict__ bth, const float* __restrict__ bph,
    const float* __restrict__ bg,
    unsigned short* __restrict__ qT, unsigned short* __restrict__ kT,
    unsigned short* __restrict__ vv)
{
  const int tid  = threadIdx.x;
  const int w    = tid >> 6;
  const int lane = tid & 63;
  const int r    = lane & 15;
  const int g    = lane >> 4;
  const int l0   = blockIdx.x * 64;
  const int b    = blockIdx.y;
  const int p    = blockIdx.z;

  __shared__ unsigned short xs[64 * 64];    // xT tile [l][c64], swizzled (8 KB)
  __shared__ unsigned short wsd[256 * 64];  // W slice [o][c64], swizzled (32 KB)

  const unsigned short* wsrc = wbf + p * 65536;

  f32x4 acc[4][4];
#pragma unroll
  for (int mi = 0; mi < 4; ++mi)
#pragma unroll
    for (int ni = 0; ni < 4; ++ni) acc[mi][ni] = f32x4{0.f, 0.f, 0.f, 0.f};

  for (int ks = 0; ks < 4; ++ks) {   // K-steps of 64 channels
    __syncthreads();
#pragma unroll
    for (int it = 0; it < 8; ++it) {
      int d  = it * 256 + w * 64 + lane;   // chunk id 0..2047
      int o  = d >> 3;
      int cs = d & 7;
      const unsigned short* src = wsrc + o * C_ + ks * 64 + ((cs ^ (o & 7)) << 3);
      gload16(src, (void*)(wsd + (size_t)(it * 256 + w * 64) * 8));
    }
#pragma unroll
    for (int it = 0; it < 16; ++it) {
      int l = (tid & 15) + 16 * (it & 3);
      int c = (tid >> 4) + 16 * (it >> 2);
      float xvv = x[((size_t)b * C_ + ks * 64 + c) * L_ + l0 + l];
      xs[l * 64 + (((c >> 3) ^ (l & 7)) << 3) + (c & 7)] = f2bf(xvv);
    }
    __syncthreads();

#pragma unroll
    for (int kk2 = 0; kk2 < 2; ++kk2) {
      short8 xf[4], wf[4];
#pragma unroll
      for (int i = 0; i < 4; ++i) {
        int lrow = 16 * i + r;
        xf[i] = *(const short8*)(xs + lrow * 64 + (((kk2 * 4 + g) ^ (lrow & 7)) << 3));
        int orow = 64 * w + 16 * i + r;
        wf[i] = *(const short8*)(wsd + orow * 64 + (((kk2 * 4 + g) ^ (orow & 7)) << 3));
      }
      if (p < 2) {
#pragma unroll
        for (int mi = 0; mi < 4; ++mi)
#pragma unroll
          for (int ni = 0; ni < 4; ++ni)
            acc[mi][ni] = __builtin_amdgcn_mfma_f32_16x16x32_bf16(xf[mi], wf[ni], acc[mi][ni], 0, 0, 0);
      } else {
#pragma unroll
        for (int mi = 0; mi < 4; ++mi)
#pragma unroll
          for (int ni = 0; ni < 4; ++ni)
            acc[mi][ni] = __builtin_amdgcn_mfma_f32_16x16x32_bf16(wf[mi], xf[ni], acc[mi][ni], 0, 0, 0);
      }
    }
  }

  if (p < 2) {
    unsigned short* dst = (p == 0) ? qT : kT;
    const float* bias   = (p == 0) ? bth : bph;
    // q carries 1/sqrt(C) * log2(e) so attention can use exp2 with no extra mul
    const float scale   = (p == 0) ? 0.09016844005556021f : 1.0f;
#pragma unroll
    for (int ni = 0; ni < 4; ++ni) {
      int o    = 64 * w + 16 * ni + r;
      float bv = bias[o];
#pragma unroll
      for (int mi = 0; mi < 4; ++mi)
#pragma unroll
        for (int rr = 0; rr < 4; ++rr) {
          int l = l0 + 16 * mi + 4 * g + rr;
          dst[((size_t)b * L_ + l) * C_ + o] = f2bf((acc[mi][ni][rr] + bv) * scale);
        }
    }
  } else {
#pragma unroll
    for (int mi = 0; mi < 4; ++mi)
#pragma unroll
      for (int rr = 0; rr < 4; ++rr) {
        int o    = 64 * w + 16 * mi + 4 * g + rr;
        float bv = bg[o];
#pragma unroll
        for (int ni = 0; ni < 4; ++ni) {
          int l = l0 + 16 * ni + r;
          vv[((size_t)b * C_ + o) * L_ + l] = f2bf(acc[mi][ni][rr] + bv);
        }
      }
  }
}

// ---------------- kernel 2: flash attention, dbuf K + raw barriers ----------------
// 4 waves = (ih = w>>1) x (jh = w&1). S'[j][i] = mfma(K,Q) (swapped). P via 8KB LDS.
// kls double-buffered: staging(t+1) issued at TOP of tile t (a full tile of slack).
// Raw s_barrier with counted waits: top = vmcnt(0)+bar; P = lgkmcnt(0)+bar (no vmem
// drain, so V gathers + staging stay in flight across it).
__global__ __launch_bounds__(256, 2) void attn_kernel(
    const unsigned short* __restrict__ qT, const unsigned short* __restrict__ kT,
    const unsigned short* __restrict__ vv,
    const float* __restrict__ x, float* __restrict__ out)
{
  const int tid  = threadIdx.x;
  const int w    = tid >> 6;
  const int lane = tid & 63;
  const int l31  = lane & 31;
  const int hi   = lane >> 5;
  const int ih   = w >> 1;
  const int jh   = w & 1;

  // XCD-aware swizzle: 512 blocks, 8 XCDs => each XCD owns 2 batches (K/V L2-resident)
  int wg = ((blockIdx.x & 7) << 6) | (blockIdx.x >> 3);
  const int i0 = (wg & 31) * 64;
  const int b  = wg >> 5;

  __shared__ unsigned short kls[2][64 * 256]; // K tiles [j][c], swizzled (2 x 32 KB)
  __shared__ unsigned short pls[64 * 64];     // P [i][j], swizzled 16B-granule (8 KB)
  __shared__ float lsums2[2][64];

  // ---- hoist Q as QK^T B-operand: col i = l31, k-slice = 8*hi per 16-ch kstep ----
  short8 qf[16];
  const unsigned short* qrow_p = qT + ((size_t)b * L_ + i0 + 32 * ih + l31) * C_;
#pragma unroll
  for (int ks = 0; ks < 16; ++ks)
    qf[ks] = *(const short8*)(qrow_p + ks * 16 + 8 * hi);

  f32x16 oacc[2][2];   // [i-tile][c-tile], D col = c = l31, rows = i pattern
#pragma unroll
  for (int it = 0; it < 2; ++it)
#pragma unroll
    for (int ct = 0; ct < 2; ++ct)
#pragma unroll
      for (int e = 0; e < 16; ++e) oacc[it][ct][e] = 0.f;
  float lsum = 0.f;

  const unsigned short* kTb = kT + (size_t)b * L_ * C_;
  const unsigned short* vvb = vv + (size_t)b * C_ * L_;

  // prologue: stage K tile 0 into buffer 0
#pragma unroll
  for (int it = 0; it < 8; ++it) {
    int d   = it * 256 + w * 64 + lane;
    int row = d >> 5;
    int cs  = d & 31;
    gload16(kTb + (size_t)row * C_ + ((cs ^ (row & 7)) << 3),
            (void*)(kls[0] + (size_t)(it * 256 + w * 64) * 8));
  }

  for (int jt = 0; jt < 32; ++jt) {
    const int j0 = jt * 64;
    const unsigned short* kcur = kls[jt & 1];

    // TOP sync: staging(jt) (issued a full tile ago) complete everywhere
    asm volatile("s_waitcnt vmcnt(0)" ::: "memory");
    __builtin_amdgcn_s_barrier();
    __builtin_amdgcn_sched_barrier(0);

    // ---- V gathers FIRST (oldest vmem -> PV waits vmcnt(8), not staging) ----
    short8 vfr[2][4];
#pragma unroll
    for (int ct = 0; ct < 2; ++ct) {
      const unsigned short* vrow = vvb + (size_t)(l31 + 32 * ct + 64 * w) * L_ + j0 + 8 * hi;
#pragma unroll
      for (int ks = 0; ks < 4; ++ks)
        vfr[ct][ks] = *(const short8*)(vrow + 16 * ks);
    }
    __builtin_amdgcn_sched_barrier(0);   // pin: V issue before staging issue

    // ---- stage K(t+1) into the other buffer; drains at NEXT top sync ----
    if (jt < 31) {
#pragma unroll
      for (int it = 0; it < 8; ++it) {
        int d   = it * 256 + w * 64 + lane;
        int row = d >> 5;
        int cs  = d & 31;
        gload16(kTb + (size_t)(j0 + 64 + row) * C_ + ((cs ^ (row & 7)) << 3),
                (void*)(kls[(jt + 1) & 1] + (size_t)(it * 256 + w * 64) * 8));
      }
    }

    // ---- S' = K Q (32x32 per wave), 2 independent MFMA chains ----
    f32x16 sacc0, sacc1;
#pragma unroll
    for (int e = 0; e < 16; ++e) { sacc0[e] = 0.f; sacc1[e] = 0.f; }
    const int jrow = l31 + 32 * jh;
#pragma unroll
    for (int ks2 = 0; ks2 < 8; ++ks2) {
      short8 kf0 = *(const short8*)(kcur + jrow * 256 + (((4 * ks2 + hi) ^ (jrow & 7)) << 3));
      short8 kf1 = *(const short8*)(kcur + jrow * 256 + (((4 * ks2 + 2 + hi) ^ (jrow & 7)) << 3));
      sacc0 = __builtin_amdgcn_mfma_f32_32x32x16_bf16(kf0, qf[2 * ks2],     sacc0, 0, 0, 0);
      sacc1 = __builtin_amdgcn_mfma_f32_32x32x16_bf16(kf1, qf[2 * ks2 + 1], sacc1, 0, 0, 0);
    }

    // ---- P = exp2(S'), pack pairs, 4x ds_write_b64 (swizzled) ----
    {
      const int i = l31 + 32 * ih;
#pragma unroll
      for (int q = 0; q < 4; ++q) {
        float p0 = exp2f(sacc0[4 * q + 0] + sacc1[4 * q + 0]);
        float p1 = exp2f(sacc0[4 * q + 1] + sacc1[4 * q + 1]);
        float p2 = exp2f(sacc0[4 * q + 2] + sacc1[4 * q + 2]);
        float p3 = exp2f(sacc0[4 * q + 3] + sacc1[4 * q + 3]);
        lsum += (p0 + p1) + (p2 + p3);
        uint2 d2;
        d2.x = (uint)f2bf(p0) | ((uint)f2bf(p1) << 16);
        d2.y = (uint)f2bf(p2) | ((uint)f2bf(p3) << 16);
        int slot = (4 * jh + q) ^ (i & 7);
        *(uint2*)(pls + i * 64 + slot * 8 + 4 * hi) = d2;
      }
    }

    // P sync: LDS writes complete + barrier (vmem stays in flight)
    asm volatile("s_waitcnt lgkmcnt(0)" ::: "memory");
    __builtin_amdgcn_s_barrier();
    __builtin_amdgcn_sched_barrier(0);

    // ---- O += P V^T (cooperative c-slice, 16 MFMA, 4 indep chains) ----
#pragma unroll
    for (int ks = 0; ks < 4; ++ks) {
      short8 pf[2];
#pragma unroll
      for (int it = 0; it < 2; ++it) {
        int irow = l31 + 32 * it;
        pf[it] = *(const short8*)(pls + irow * 64 + (((2 * ks + hi) ^ (irow & 7)) << 3));
      }
#pragma unroll
      for (int it = 0; it < 2; ++it)
#pragma unroll
        for (int ct = 0; ct < 2; ++ct)
          oacc[it][ct] = __builtin_amdgcn_mfma_f32_32x32x16_bf16(pf[it], vfr[ct][ks], oacc[it][ct], 0, 0, 0);
    }
  }

  // ---- lsum: lanes l and l+32 hold same i; combine, then cross-wave via LDS ----
  lsum += __shfl_xor(lsum, 32);
  if (lane < 32) lsums2[jh][32 * ih + l31] = lsum;
  __syncthreads();

  // ---- epilogue: out = x + O / lsum ----
#pragma unroll
  for (int it = 0; it < 2; ++it)
#pragma unroll
    for (int q = 0; q < 4; ++q) {
      int ib = 32 * it + 8 * q + 4 * hi;
      f32x4 ls0 = *(const f32x4*)(&lsums2[0][ib]);
      f32x4 ls1 = *(const f32x4*)(&lsums2[1][ib]);
      f32x4 linv;
#pragma unroll
      for (int rr = 0; rr < 4; ++rr) linv[rr] = 1.0f / (ls0[rr] + ls1[rr]);
#pragma unroll
      for (int ct = 0; ct < 2; ++ct) {
        int c = l31 + 32 * ct + 64 * w;
        size_t base = ((size_t)b * C_ + c) * L_ + i0 + ib;
        f32x4 xv = *(const f32x4*)(x + base);
        f32x4 ov;
#pragma unroll
        for (int rr = 0; rr < 4; ++rr)
          ov[rr] = xv[rr] + oacc[it][ct][4 * q + rr] * linv[rr];
        *(f32x4*)(out + base) = ov;
      }
    }
}

extern "C" void kernel_launch(void* const* d_in, const int* in_sizes, int n_in,
                              void* d_out, int out_size, void* d_ws, size_t ws_size,
                              hipStream_t stream) {
  (void)in_sizes; (void)n_in; (void)out_size; (void)ws_size;
  const float* x   = (const float*)d_in[0];
  const float* wt  = (const float*)d_in[1];
  const float* bt  = (const float*)d_in[2];
  const float* wp  = (const float*)d_in[3];
  const float* bp  = (const float*)d_in[4];
  const float* wg  = (const float*)d_in[5];
  const float* bgg = (const float*)d_in[6];
  float* out = (float*)d_out;

  char* ws = (char*)d_ws;
  unsigned short* wbf = (unsigned short*)ws;                              // 384 KB
  unsigned short* qT  = (unsigned short*)(ws + 393216);                   // 16 MB
  unsigned short* kT  = (unsigned short*)(ws + 393216 + 16777216);        // 16 MB
  unsigned short* vv  = (unsigned short*)(ws + 393216 + 2 * 16777216);    // 16 MB

  convert_w<<<dim3(256), dim3(256), 0, stream>>>(wt, wp, wg, wbf);
  proj_kernel<<<dim3(32, 16, 3), dim3(256), 0, stream>>>(x, wbf, bt, bp, bgg, qT, kT, vv);
  attn_kernel<<<dim3(512), dim3(256), 0, stream>>>(qT, kT, vv, x, out);
}

// Round 6
// 141.553 us; speedup vs baseline: 1.2269x; 1.2269x over previous
//
#include <hip/hip_runtime.h>
#include <math.h>

#define B_ 16
#define C_ 256
#define L_ 2048

using short8 = __attribute__((ext_vector_type(8))) short;
using f32x4  = __attribute__((ext_vector_type(4))) float;
using f32x16 = __attribute__((ext_vector_type(16))) float;
typedef unsigned int uint;

__device__ __forceinline__ unsigned short f2bf(float f) {
  unsigned u = __float_as_uint(f);
  return (unsigned short)((u + 0x7FFFu + ((u >> 16) & 1u)) >> 16);
}

__device__ __forceinline__ void gload16(const void* src, void* dst) {
  __builtin_amdgcn_global_load_lds(
      (const __attribute__((address_space(1))) unsigned int*)src,
      (__attribute__((address_space(3))) unsigned int*)dst, 16, 0, 0);
}

// ---------------- kernel 0: convert weights fp32 -> bf16 ----------------
__global__ __launch_bounds__(256) void convert_w(const float* __restrict__ wt,
                                                 const float* __restrict__ wp,
                                                 const float* __restrict__ wg,
                                                 unsigned short* __restrict__ dst) {
  int i = blockIdx.x * 256 + threadIdx.x;          // 65536 per matrix
  dst[i]          = f2bf(wt[i]);
  dst[65536 + i]  = f2bf(wp[i]);
  dst[131072 + i] = f2bf(wg[i]);
}

// ---------------- kernel 1: fused QKV projection ----------------
// p=0: qT[b,l,o] = (W_theta x + b_theta) * log2e/16   (bf16, [B,L,C])
// p=1: kT[b,l,o] =  W_phi   x + b_phi                 (bf16, [B,L,C])
// p=2: v [b,o,l] =  W_g     x + b_g                   (bf16, [B,C,L])
__global__ __launch_bounds__(256, 2) void proj_kernel(
    const float* __restrict__ x, const unsigned short* __restrict__ wbf,
    const float* __restrict__ bth, const float* __restrict__ bph,
    const float* __restrict__ bg,
    unsigned short* __restrict__ qT, unsigned short* __restrict__ kT,
    unsigned short* __restrict__ vv)
{
  const int tid  = threadIdx.x;
  const int w    = tid >> 6;
  const int lane = tid & 63;
  const int r    = lane & 15;
  const int g    = lane >> 4;
  const int l0   = blockIdx.x * 64;
  const int b    = blockIdx.y;
  const int p    = blockIdx.z;

  __shared__ unsigned short xs[64 * 64];    // xT tile [l][c64], swizzled (8 KB)
  __shared__ unsigned short wsd[256 * 64];  // W slice [o][c64], swizzled (32 KB)

  const unsigned short* wsrc = wbf + p * 65536;

  f32x4 acc[4][4];
#pragma unroll
  for (int mi = 0; mi < 4; ++mi)
#pragma unroll
    for (int ni = 0; ni < 4; ++ni) acc[mi][ni] = f32x4{0.f, 0.f, 0.f, 0.f};

  for (int ks = 0; ks < 4; ++ks) {   // K-steps of 64 channels
    __syncthreads();
#pragma unroll
    for (int it = 0; it < 8; ++it) {
      int d  = it * 256 + w * 64 + lane;   // chunk id 0..2047
      int o  = d >> 3;
      int cs = d & 7;
      const unsigned short* src = wsrc + o * C_ + ks * 64 + ((cs ^ (o & 7)) << 3);
      gload16(src, (void*)(wsd + (size_t)(it * 256 + w * 64) * 8));
    }
#pragma unroll
    for (int it = 0; it < 16; ++it) {
      int l = (tid & 15) + 16 * (it & 3);
      int c = (tid >> 4) + 16 * (it >> 2);
      float xvv = x[((size_t)b * C_ + ks * 64 + c) * L_ + l0 + l];
      xs[l * 64 + (((c >> 3) ^ (l & 7)) << 3) + (c & 7)] = f2bf(xvv);
    }
    __syncthreads();

#pragma unroll
    for (int kk2 = 0; kk2 < 2; ++kk2) {
      short8 xf[4], wf[4];
#pragma unroll
      for (int i = 0; i < 4; ++i) {
        int lrow = 16 * i + r;
        xf[i] = *(const short8*)(xs + lrow * 64 + (((kk2 * 4 + g) ^ (lrow & 7)) << 3));
        int orow = 64 * w + 16 * i + r;
        wf[i] = *(const short8*)(wsd + orow * 64 + (((kk2 * 4 + g) ^ (orow & 7)) << 3));
      }
      if (p < 2) {
#pragma unroll
        for (int mi = 0; mi < 4; ++mi)
#pragma unroll
          for (int ni = 0; ni < 4; ++ni)
            acc[mi][ni] = __builtin_amdgcn_mfma_f32_16x16x32_bf16(xf[mi], wf[ni], acc[mi][ni], 0, 0, 0);
      } else {
#pragma unroll
        for (int mi = 0; mi < 4; ++mi)
#pragma unroll
          for (int ni = 0; ni < 4; ++ni)
            acc[mi][ni] = __builtin_amdgcn_mfma_f32_16x16x32_bf16(wf[mi], xf[ni], acc[mi][ni], 0, 0, 0);
      }
    }
  }

  if (p < 2) {
    unsigned short* dst = (p == 0) ? qT : kT;
    const float* bias   = (p == 0) ? bth : bph;
    // q carries 1/sqrt(C) * log2(e) so attention can use exp2 with no extra mul
    const float scale   = (p == 0) ? 0.09016844005556021f : 1.0f;
#pragma unroll
    for (int ni = 0; ni < 4; ++ni) {
      int o    = 64 * w + 16 * ni + r;
      float bv = bias[o];
#pragma unroll
      for (int mi = 0; mi < 4; ++mi)
#pragma unroll
        for (int rr = 0; rr < 4; ++rr) {
          int l = l0 + 16 * mi + 4 * g + rr;
          dst[((size_t)b * L_ + l) * C_ + o] = f2bf((acc[mi][ni][rr] + bv) * scale);
        }
    }
  } else {
#pragma unroll
    for (int mi = 0; mi < 4; ++mi)
#pragma unroll
      for (int rr = 0; rr < 4; ++rr) {
        int o    = 64 * w + 16 * mi + 4 * g + rr;
        float bv = bg[o];
#pragma unroll
        for (int ni = 0; ni < 4; ++ni) {
          int l = l0 + 16 * ni + r;
          vv[((size_t)b * C_ + o) * L_ + l] = f2bf(acc[mi][ni][rr] + bv);
        }
      }
  }
}

// ---------------- kernel 2: flash attention, dbuf K, __syncthreads-managed ----------------
// Round-4 structure + kls double-buffer; staging(t+1) issued at top (after V gathers,
// which stay oldest in the vmem FIFO). Single drain point = the P-__syncthreads, with
// QK^T+softmax (~600 cyc) of slack. No inline asm, no sched_barriers.
__global__ __launch_bounds__(256, 2) void attn_kernel(
    const unsigned short* __restrict__ qT, const unsigned short* __restrict__ kT,
    const unsigned short* __restrict__ vv,
    const float* __restrict__ x, float* __restrict__ out)
{
  const int tid  = threadIdx.x;
  const int w    = tid >> 6;
  const int lane = tid & 63;
  const int l31  = lane & 31;
  const int hi   = lane >> 5;
  const int ih   = w >> 1;
  const int jh   = w & 1;

  // XCD-aware swizzle: 512 blocks, 8 XCDs => each XCD owns 2 batches (K/V L2-resident)
  int wg = ((blockIdx.x & 7) << 6) | (blockIdx.x >> 3);
  const int i0 = (wg & 31) * 64;
  const int b  = wg >> 5;

  __shared__ unsigned short kls[2][64 * 256]; // K tiles [j][c], swizzled (2 x 32 KB)
  __shared__ unsigned short pls[64 * 64];     // P [i][j], swizzled 16B-granule (8 KB)
  __shared__ float lsums2[2][64];

  // ---- hoist Q as QK^T B-operand: col i = l31, k-slice = 8*hi per 16-ch kstep ----
  short8 qf[16];
  const unsigned short* qrow_p = qT + ((size_t)b * L_ + i0 + 32 * ih + l31) * C_;
#pragma unroll
  for (int ks = 0; ks < 16; ++ks)
    qf[ks] = *(const short8*)(qrow_p + ks * 16 + 8 * hi);

  f32x16 oacc[2][2];   // [i-tile][c-tile], D col = c = l31, rows = i pattern
#pragma unroll
  for (int it = 0; it < 2; ++it)
#pragma unroll
    for (int ct = 0; ct < 2; ++ct)
#pragma unroll
      for (int e = 0; e < 16; ++e) oacc[it][ct][e] = 0.f;
  float lsum = 0.f;

  const unsigned short* kTb = kT + (size_t)b * L_ * C_;
  const unsigned short* vvb = vv + (size_t)b * C_ * L_;

  // prologue: stage K tile 0 into buffer 0
#pragma unroll
  for (int it = 0; it < 8; ++it) {
    int d   = it * 256 + w * 64 + lane;
    int row = d >> 5;
    int cs  = d & 31;
    gload16(kTb + (size_t)row * C_ + ((cs ^ (row & 7)) << 3),
            (void*)(kls[0] + (size_t)(it * 256 + w * 64) * 8));
  }

  for (int jt = 0; jt < 32; ++jt) {
    const int j0 = jt * 64;
    const unsigned short* kcur = kls[jt & 1];

    __syncthreads();   // kls(jt) ready everywhere; prev PV's pls reads done

    // ---- V gathers FIRST (oldest vmem -> PV's wait leaves staging in flight) ----
    short8 vfr[2][4];
#pragma unroll
    for (int ct = 0; ct < 2; ++ct) {
      const unsigned short* vrow = vvb + (size_t)(l31 + 32 * ct + 64 * w) * L_ + j0 + 8 * hi;
#pragma unroll
      for (int ks = 0; ks < 4; ++ks)
        vfr[ct][ks] = *(const short8*)(vrow + 16 * ks);
    }

    // ---- stage K(t+1) into the other buffer; drains at the P-__syncthreads ----
    if (jt < 31) {
#pragma unroll
      for (int it = 0; it < 8; ++it) {
        int d   = it * 256 + w * 64 + lane;
        int row = d >> 5;
        int cs  = d & 31;
        gload16(kTb + (size_t)(j0 + 64 + row) * C_ + ((cs ^ (row & 7)) << 3),
                (void*)(kls[(jt + 1) & 1] + (size_t)(it * 256 + w * 64) * 8));
      }
    }

    // ---- S' = K Q (32x32 per wave), 2 independent MFMA chains ----
    f32x16 sacc0, sacc1;
#pragma unroll
    for (int e = 0; e < 16; ++e) { sacc0[e] = 0.f; sacc1[e] = 0.f; }
    const int jrow = l31 + 32 * jh;
#pragma unroll
    for (int ks2 = 0; ks2 < 8; ++ks2) {
      short8 kf0 = *(const short8*)(kcur + jrow * 256 + (((4 * ks2 + hi) ^ (jrow & 7)) << 3));
      short8 kf1 = *(const short8*)(kcur + jrow * 256 + (((4 * ks2 + 2 + hi) ^ (jrow & 7)) << 3));
      sacc0 = __builtin_amdgcn_mfma_f32_32x32x16_bf16(kf0, qf[2 * ks2],     sacc0, 0, 0, 0);
      sacc1 = __builtin_amdgcn_mfma_f32_32x32x16_bf16(kf1, qf[2 * ks2 + 1], sacc1, 0, 0, 0);
    }

    // ---- P = exp2(S'), pack pairs, 4x ds_write_b64 (swizzled) ----
    {
      const int i = l31 + 32 * ih;
#pragma unroll
      for (int q = 0; q < 4; ++q) {
        float p0 = exp2f(sacc0[4 * q + 0] + sacc1[4 * q + 0]);
        float p1 = exp2f(sacc0[4 * q + 1] + sacc1[4 * q + 1]);
        float p2 = exp2f(sacc0[4 * q + 2] + sacc1[4 * q + 2]);
        float p3 = exp2f(sacc0[4 * q + 3] + sacc1[4 * q + 3]);
        lsum += (p0 + p1) + (p2 + p3);
        uint2 d2;
        d2.x = (uint)f2bf(p0) | ((uint)f2bf(p1) << 16);
        d2.y = (uint)f2bf(p2) | ((uint)f2bf(p3) << 16);
        int slot = (4 * jh + q) ^ (i & 7);
        *(uint2*)(pls + i * 64 + slot * 8 + 4 * hi) = d2;
      }
    }
    __syncthreads();   // P visible; drains V (needed now) + staging (had full QK^T window)

    // ---- O += P V^T (cooperative c-slice, 16 MFMA) ----
#pragma unroll
    for (int ks = 0; ks < 4; ++ks) {
      short8 pf[2];
#pragma unroll
      for (int it = 0; it < 2; ++it) {
        int irow = l31 + 32 * it;
        pf[it] = *(const short8*)(pls + irow * 64 + (((2 * ks + hi) ^ (irow & 7)) << 3));
      }
#pragma unroll
      for (int it = 0; it < 2; ++it)
#pragma unroll
        for (int ct = 0; ct < 2; ++ct)
          oacc[it][ct] = __builtin_amdgcn_mfma_f32_32x32x16_bf16(pf[it], vfr[ct][ks], oacc[it][ct], 0, 0, 0);
    }
  }

  // ---- lsum: lanes l and l+32 hold same i; combine, then cross-wave via LDS ----
  lsum += __shfl_xor(lsum, 32);
  if (lane < 32) lsums2[jh][32 * ih + l31] = lsum;
  __syncthreads();

  // ---- epilogue: out = x + O / lsum ----
#pragma unroll
  for (int it = 0; it < 2; ++it)
#pragma unroll
    for (int q = 0; q < 4; ++q) {
      int ib = 32 * it + 8 * q + 4 * hi;
      f32x4 ls0 = *(const f32x4*)(&lsums2[0][ib]);
      f32x4 ls1 = *(const f32x4*)(&lsums2[1][ib]);
      f32x4 linv;
#pragma unroll
      for (int rr = 0; rr < 4; ++rr) linv[rr] = 1.0f / (ls0[rr] + ls1[rr]);
#pragma unroll
      for (int ct = 0; ct < 2; ++ct) {
        int c = l31 + 32 * ct + 64 * w;
        size_t base = ((size_t)b * C_ + c) * L_ + i0 + ib;
        f32x4 xv = *(const f32x4*)(x + base);
        f32x4 ov;
#pragma unroll
        for (int rr = 0; rr < 4; ++rr)
          ov[rr] = xv[rr] + oacc[it][ct][4 * q + rr] * linv[rr];
        *(f32x4*)(out + base) = ov;
      }
    }
}

extern "C" void kernel_launch(void* const* d_in, const int* in_sizes, int n_in,
                              void* d_out, int out_size, void* d_ws, size_t ws_size,
                              hipStream_t stream) {
  (void)in_sizes; (void)n_in; (void)out_size; (void)ws_size;
  const float* x   = (const float*)d_in[0];
  const float* wt  = (const float*)d_in[1];
  const float* bt  = (const float*)d_in[2];
  const float* wp  = (const float*)d_in[3];
  const float* bp  = (const float*)d_in[4];
  const float* wg  = (const float*)d_in[5];
  const float* bgg = (const float*)d_in[6];
  float* out = (float*)d_out;

  char* ws = (char*)d_ws;
  unsigned short* wbf = (unsigned short*)ws;                              // 384 KB
  unsigned short* qT  = (unsigned short*)(ws + 393216);                   // 16 MB
  unsigned short* kT  = (unsigned short*)(ws + 393216 + 16777216);        // 16 MB
  unsigned short* vv  = (unsigned short*)(ws + 393216 + 2 * 16777216);    // 16 MB

  convert_w<<<dim3(256), dim3(256), 0, stream>>>(wt, wp, wg, wbf);
  proj_kernel<<<dim3(32, 16, 3), dim3(256), 0, stream>>>(x, wbf, bt, bp, bgg, qT, kT, vv);
  attn_kernel<<<dim3(512), dim3(256), 0, stream>>>(qT, kT, vv, x, out);
}